// Round 17
// baseline (7193.421 us; speedup 1.0000x reference)
//
#include <hip/hip_runtime.h>
#include <cstdint>
#include <cstddef>

#define B_ 64
#define T_ 1024
#define D_ 1024
#define NBLK 256

typedef __attribute__((ext_vector_type(8))) _Float16 half8;
typedef __attribute__((ext_vector_type(4))) float f32x4;
typedef unsigned int u32;
typedef unsigned long long u64;
typedef unsigned short u16;

static __device__ __forceinline__ f32x4 mfma16(half8 a, half8 b, f32x4 c) {
  return __builtin_amdgcn_mfma_f32_16x16x32_f16(a, b, c, 0, 0, 0);
}
static __device__ __forceinline__ u64 cohl64(const u64* p) {
  return __hip_atomic_load(p, __ATOMIC_RELAXED, __HIP_MEMORY_SCOPE_AGENT);
}
static __device__ __forceinline__ u32 cohl32(const u32* p) {
  return __hip_atomic_load(p, __ATOMIC_RELAXED, __HIP_MEMORY_SCOPE_AGENT);
}
static __device__ __forceinline__ void cohs32(u32* p, u32 v) {
  __hip_atomic_store(p, v, __ATOMIC_RELAXED, __HIP_MEMORY_SCOPE_AGENT);
}
static __device__ __forceinline__ u16 h2u(_Float16 h) {
  return __builtin_bit_cast(u16, h);
}

// ---- staging: 32 rows x 1024 fp16 -> regs -> LDS (XOR-swizzled) ----------
// 512 threads: thread t covers rows r=t>>5 and r+16, chunk j=t&31.

static __device__ __forceinline__ void stage_coh(const _Float16* src, u64* st, int tid) {
  const int r = tid >> 5, j = tid & 31;
  const u64* p0 = (const u64*)(src + (size_t)r * D_) + j * 2;
  const u64* p1 = (const u64*)(src + (size_t)(r + 16) * D_) + j * 2;
  #pragma unroll
  for (int k = 0; k < 4; ++k) {
    st[2 * k] = cohl64(p0 + k * 64);
    st[2 * k + 1] = cohl64(p0 + k * 64 + 1);
    st[8 + 2 * k] = cohl64(p1 + k * 64);
    st[8 + 2 * k + 1] = cohl64(p1 + k * 64 + 1);
  }
}
static __device__ __forceinline__ void stage_x(const _Float16* src, u64* st, int tid) {
  const int r = tid >> 5, j = tid & 31;
  const u64* p0 = (const u64*)(src + (size_t)r * T_ * D_) + j * 2;
  const u64* p1 = (const u64*)(src + (size_t)(r + 16) * T_ * D_) + j * 2;
  #pragma unroll
  for (int k = 0; k < 4; ++k) {
    st[2 * k] = p0[k * 64];
    st[2 * k + 1] = p0[k * 64 + 1];
    st[8 + 2 * k] = p1[k * 64];
    st[8 + 2 * k + 1] = p1[k * 64 + 1];
  }
}
static __device__ __forceinline__ void stage_xf(const float* src, u64* st, int tid) {
  const int r = tid >> 5, j = tid & 31;
  #pragma unroll
  for (int h = 0; h < 2; ++h) {
    const float4* p = (const float4*)(src + (size_t)(r + h * 16) * T_ * D_) + j * 2;
    #pragma unroll
    for (int k = 0; k < 4; ++k) {
      #pragma unroll
      for (int q = 0; q < 2; ++q) {
        float4 v = p[k * 64 + q];
        union { u16 us[4]; u64 u; } pk;
        pk.us[0] = h2u((_Float16)v.x); pk.us[1] = h2u((_Float16)v.y);
        pk.us[2] = h2u((_Float16)v.z); pk.us[3] = h2u((_Float16)v.w);
        st[h * 8 + 2 * k + q] = pk.u;
      }
    }
  }
}
static __device__ __forceinline__ void stage_write(char* lds, const u64* st, int tid) {
  const int r = tid >> 5, j = tid & 31;
  #pragma unroll
  for (int h = 0; h < 2; ++h) {
    const int rr = r + h * 16;
    const int sw = (rr & 7) << 4;
    char* row = lds + rr * 2048;
    #pragma unroll
    for (int k = 0; k < 4; ++k) {
      char* dst = row + ((j * 16 + k * 512) ^ sw);
      *(u64*)dst = st[h * 8 + 2 * k];
      *(u64*)(dst + 8) = st[h * 8 + 2 * k + 1];
    }
  }
}

// ---- GEMM: gate-pair, weights pinned in regs. 1 A-pair -> 4 MFMAs --------
static __device__ __forceinline__ void gemm_gp(
    f32x4* acc, const char* ldsA, const half8* wA, const half8* wBv,
    int kq, int lane) {
  const int r = lane & 15;
  const int kl2 = (lane >> 4) << 4;
  const int sw = (r & 7) << 4;
  const char* p0 = ldsA + r * 2048;
  const char* p1 = ldsA + (16 + r) * 2048;   // (16+r)&7 == r&7: same swizzle
  #pragma unroll
  for (int ks = 0; ks < 8; ++ks) {
    const int kb = (kq * 512 + ks * 64 + kl2) ^ sw;
    half8 a0 = *(const half8*)(p0 + kb);
    half8 a1 = *(const half8*)(p1 + kb);
    acc[0] = mfma16(a0, wA[ks], acc[0]);
    acc[1] = mfma16(a1, wA[ks], acc[1]);
    acc[2] = mfma16(a0, wBv[ks], acc[2]);
    acc[3] = mfma16(a1, wBv[ks], acc[3]);
  }
}

// ---- tree wait: 8 lanes poll ONE 64B done-line, per-lane targets ---------
// done[g]: group g (= bids [32g,32g+31]) fully arrived. Groups: 0,1=lyr0/mh0
// 2,3=lyr0/mh1  4,5=lyr1/mh0  6,7=lyr1/mh1.
// lyr0 waits own-mh lyr0 groups >= s (h0 dep) + own-mh lyr1 >= s-4 (throttle,
// skew<=5 < rot depth 8). lyr1 waits own-mh lyr0 and lyr1 groups >= s.
static __device__ __forceinline__ void treewait(const u32* done, int lyr,
                                                int mh, int s, int tid) {
  if (tid < 8) {
    const int gl = tid >> 2;           // group's layer
    const int gm = (tid >> 1) & 1;     // group's mh
    u32 tgt = 0;
    if (gm == mh)
      tgt = (gl == lyr) ? (u32)s
          : (lyr == 0) ? (u32)(s > 4 ? s - 4 : 0) : (u32)s;
    if (tgt > 0) {
      int spin = 0;
      while (cohl32(done + tid) < tgt && ++spin < (1 << 16))
        __builtin_amdgcn_s_sleep(2);
    }
  }
  __syncthreads();
}

// ---- persistent kernel ---------------------------------------------------
// 256 blocks x 512 threads; block map = r13/r16. 8 waves = (kq)x(gp),
// weights pinned (r16). LDS: bufA 64KB + bufB 64KB; glp ALIASES bufA
// (bufA dead after GEMM1: all reads complete before sync B).
// lyr0: stage x + GEMM1 BEFORE the wait (barrier-independent) -> GEMM1
// hides under barrier skew. lyr1: h1-load latency hides under GEMM1.
// Barrier: tree (arrive->slot; first-of-group gathers -> done[g]; consumers
// poll one line). Bounded spins everywhere.

template <bool XPRE>
__global__ __launch_bounds__(512, 2) void lstm_persist(
    const float* __restrict__ x32, const _Float16* __restrict__ xh,
    const _Float16* __restrict__ W,
    _Float16* h0,                  // [8 rot][B][D]
    _Float16* h1,                  // [2 parity][B][D]
    float* __restrict__ out, u32* slots, u32* done)
{
  __shared__ char bufA[65536];
  __shared__ char bufB[65536];
  float (*glp)[32][68] = (float (*)[32][68])bufA;   // alias (bufA dead)

  const int tid = threadIdx.x;
  const int lane = tid & 63;
  const int wv = tid >> 6;                 // 0..7
  const int kq = wv >> 1;
  const int gp = wv & 1;
  const int bid = blockIdx.x;
  const int slot = bid >> 3;
  const int lyr = slot >> 4;
  const int mh = (slot >> 3) & 1;
  const int dgrp = (bid & 7) * 8 + (slot & 7);
  const int d0 = dgrp << 4;
  const int mbase = mh << 5;
  const int r = lane & 15;
  const int klane = lane >> 4;

  // ---- weight preload: 2 gates x (Wih+Whh) = 32 half8, pinned ----
  const _Float16* Wih = W + (size_t)(2 * lyr) * 4096 * 1024;
  const _Float16* Whh = Wih + (size_t)4096 * 1024;
  const size_t row0 = (size_t)((gp * 2) * 1024 + d0 + r) * 1024 + kq * 256 + klane * 8;
  const size_t row1 = (size_t)((gp * 2 + 1) * 1024 + d0 + r) * 1024 + kq * 256 + klane * 8;
  half8 wihA[8], wihB[8], whhA[8], whhB[8];
  #pragma unroll
  for (int ks = 0; ks < 8; ++ks) {
    wihA[ks] = *(const half8*)(Wih + row0 + ks * 32);
    wihB[ks] = *(const half8*)(Wih + row1 + ks * 32);
    whhA[ks] = *(const half8*)(Whh + row0 + ks * 32);
    whhB[ks] = *(const half8*)(Whh + row1 + ks * 32);
  }
  #pragma unroll
  for (int ks = 0; ks < 8; ++ks) {
    asm volatile("" : "+v"(wihA[ks]));
    asm volatile("" : "+v"(wihB[ks]));
    asm volatile("" : "+v"(whhA[ks]));
    asm volatile("" : "+v"(whhB[ks]));
  }

  float creg0 = 0.f, creg1 = 0.f;
  const int cb = tid >> 3;
  const int cd = (tid & 7) << 1;
  const size_t HS = (size_t)B_ * D_;
  const int g = bid >> 5;                  // my barrier group
  const bool gatherer = (bid & 31) == 0;

  u64 st[16];
  if (lyr == 0) {
    if (XPRE) stage_x(xh + (size_t)mbase * T_ * D_, st, tid);
    else      stage_xf(x32 + (size_t)mbase * T_ * D_, st, tid);
  }

  for (int s = 0; s <= T_; ++s) {
    const bool active = lyr ? (s >= 1) : (s < T_);
    const int t = lyr ? (s - 1) : s;
    const _Float16* h0prev = h0 + (size_t)((s + 7) & 7) * HS + (size_t)mbase * D_;

    f32x4 acc[4];
    #pragma unroll
    for (int i = 0; i < 4; ++i) acc[i] = (f32x4){0.f, 0.f, 0.f, 0.f};

    if (lyr == 0) {
      if (active) {
        stage_write(bufA, st, tid);              // x[t] (prefetched regs)
        __syncthreads();                         // A: bufA ready
        gemm_gp(acc, bufA, wihA, wihB, kq, lane);// GEMM1 pre-wait
      }
      treewait(done, 0, mh, s, tid);             // also fences gemm1 reads
      if (active) {
        stage_coh(h0prev, st, tid);              // h0[s-1] (now ready)
        stage_write(bufB, st, tid);
        __syncthreads();                         // B: bufB ready
        gemm_gp(acc, bufB, whhA, whhB, kq, lane);
      }
    } else {
      treewait(done, 1, mh, s, tid);
      if (active) {
        stage_coh(h0prev, st, tid);              // h0[t] from layer 0
        stage_write(bufA, st, tid);
        __syncthreads();                         // A
        stage_coh(h1 + (size_t)(s & 1) * HS + (size_t)mbase * D_, st, tid);
        gemm_gp(acc, bufA, wihA, wihB, kq, lane);// h1 latency hides here
        stage_write(bufB, st, tid);
        __syncthreads();                         // B: bufB ready, bufA dead
        gemm_gp(acc, bufB, whhA, whhB, kq, lane);
      }
    }

    if (active) {
      // partials -> glp (aliases bufA; all bufA reads done before sync B)
      {
        const int r4 = klane << 2;
        const int c0 = (gp * 2) * 16 + r;
        #pragma unroll
        for (int i = 0; i < 4; ++i) {
          glp[kq][r4 + i][c0]           = acc[0][i];
          glp[kq][16 + r4 + i][c0]      = acc[1][i];
          glp[kq][r4 + i][c0 + 16]      = acc[2][i];
          glp[kq][16 + r4 + i][c0 + 16] = acc[3][i];
        }
      }
      __syncthreads();                           // C: glp ready

      if (tid < 256) {
        float g4[4][2];
        #pragma unroll
        for (int gg = 0; gg < 4; ++gg) {
          g4[gg][0] = glp[0][cb][gg * 16 + cd] + glp[1][cb][gg * 16 + cd]
                    + glp[2][cb][gg * 16 + cd] + glp[3][cb][gg * 16 + cd];
          g4[gg][1] = glp[0][cb][gg * 16 + cd + 1] + glp[1][cb][gg * 16 + cd + 1]
                    + glp[2][cb][gg * 16 + cd + 1] + glp[3][cb][gg * 16 + cd + 1];
        }
        const float i0 = 1.f / (1.f + expf(-g4[0][0])), i1 = 1.f / (1.f + expf(-g4[0][1]));
        const float f0 = 1.f / (1.f + expf(-g4[1][0])), f1 = 1.f / (1.f + expf(-g4[1][1]));
        const float z0 = tanhf(g4[2][0]),               z1 = tanhf(g4[2][1]);
        const float o0 = 1.f / (1.f + expf(-g4[3][0])), o1 = 1.f / (1.f + expf(-g4[3][1]));
        creg0 = f0 * creg0 + i0 * z0;
        creg1 = f1 * creg1 + i1 * z1;
        const float hn0 = o0 * tanhf(creg0);
        const float hn1 = o1 * tanhf(creg1);
        union { u16 us[2]; u32 u; } pk;
        pk.us[0] = h2u((_Float16)hn0);
        pk.us[1] = h2u((_Float16)hn1);
        _Float16* hw = lyr
            ? (h1 + (size_t)((s + 1) & 1) * HS)
            : (h0 + (size_t)(s & 7) * HS);
        cohs32((u32*)(hw + (size_t)(mbase + cb) * D_ + d0 + cd), pk.u);
        if (lyr) {
          float2 o2; o2.x = hn0; o2.y = hn1;
          *(float2*)(out + ((size_t)(mbase + cb) * T_ + t) * D_ + d0 + cd) = o2;
        }
      }
    }

    // drain sc1 h stores (syncthreads emits vmcnt(0) per wave), then arrive
    __syncthreads();                             // D
    if (tid == 0) cohs32(slots + bid * 32, (u32)(s + 1));

    // gatherer (first block of own group): aggregate 32 slots -> done[g]
    if (gatherer) {
      if (tid < 32) {
        const u32* p = slots + (g * 32 + tid) * 32;
        int spin = 0;
        while (cohl32(p) < (u32)(s + 1) && ++spin < (1 << 18))
          __builtin_amdgcn_s_sleep(1);
      }
      if (tid == 0) cohs32(done + g, (u32)(s + 1));
    }

    // prefetch next x (after arrive/publish)
    if (lyr == 0 && s + 1 < T_) {
      if (XPRE) stage_x(xh + ((size_t)mbase * T_ + (s + 1)) * D_, st, tid);
      else      stage_xf(x32 + ((size_t)mbase * T_ + (s + 1)) * D_, st, tid);
    }
  }
}

// ---- setup ---------------------------------------------------------------
__global__ void convw(const float* __restrict__ w0, const float* __restrict__ w1,
                      const float* __restrict__ w2, const float* __restrict__ w3,
                      u64* __restrict__ dst) {
  const size_t n1 = (size_t)D_ * D_;
  const size_t n = 4 * n1;
  for (size_t i = (size_t)blockIdx.x * blockDim.x + threadIdx.x; i < n;
       i += (size_t)gridDim.x * blockDim.x) {
    const size_t m = i / n1, j = i - m * n1;
    const float* src = (m == 0) ? w0 : (m == 1) ? w1 : (m == 2) ? w2 : w3;
    float4 v = ((const float4*)src)[j];
    union { u16 us[4]; u64 u; } pk;
    pk.us[0] = h2u((_Float16)v.x); pk.us[1] = h2u((_Float16)v.y);
    pk.us[2] = h2u((_Float16)v.z); pk.us[3] = h2u((_Float16)v.w);
    dst[i] = pk.u;
  }
}
__global__ void convx(const float* __restrict__ x, u64* __restrict__ xh) {
  const size_t n = (size_t)B_ * T_ * D_ / 4;
  for (size_t i = (size_t)blockIdx.x * blockDim.x + threadIdx.x; i < n;
       i += (size_t)gridDim.x * blockDim.x) {
    float4 v = ((const float4*)x)[i];
    union { u16 us[4]; u64 u; } pk;
    pk.us[0] = h2u((_Float16)v.x); pk.us[1] = h2u((_Float16)v.y);
    pk.us[2] = h2u((_Float16)v.z); pk.us[3] = h2u((_Float16)v.w);
    xh[i] = pk.u;
  }
}

// ---- host ----------------------------------------------------------------
extern "C" void kernel_launch(void* const* d_in, const int* in_sizes, int n_in,
                              void* d_out, int out_size, void* d_ws, size_t ws_size,
                              hipStream_t stream) {
  (void)in_sizes; (void)n_in; (void)out_size;
  const float* x = (const float*)d_in[0];
  const float* Wih0 = (const float*)d_in[1];
  const float* Whh0 = (const float*)d_in[2];
  const float* Wih1 = (const float*)d_in[3];
  const float* Whh1 = (const float*)d_in[4];
  float* out = (float*)d_out;

  char* ws = (char*)d_ws;
  const size_t MB = 1ull << 20;
  const size_t KB = 1024;
  // layout: [0,32MB) W fp16
  //   32MB: h0 rot8 1MB | 33MB: h1 256KB | +256KB: slots 32KB + done 64B
  //   35MB: xh 128MB
  _Float16* Wf = (_Float16*)ws;
  _Float16* h0 = (_Float16*)(ws + 32 * MB);
  _Float16* h1 = (_Float16*)(ws + 33 * MB);
  u32* slots = (u32*)(ws + 33 * MB + 256 * KB);   // 256 x 128B
  u32* done = slots + 8192;                       // one 64B line
  _Float16* xh = (_Float16*)(ws + 35 * MB);
  const bool xpre = ws_size >= 35 * MB + (size_t)B_ * T_ * D_ * 2;

  hipMemsetAsync(ws + 32 * MB, 0, 1 * MB + 256 * KB + 33 * KB, stream);
  convw<<<4096, 256, 0, stream>>>(Wih0, Whh0, Wih1, Whh1, (u64*)Wf);
  if (xpre) {
    convx<<<4096, 256, 0, stream>>>(x, (u64*)xh);
    lstm_persist<true><<<NBLK, 512, 0, stream>>>(x, xh, Wf, h0, h1, out, slots, done);
  } else {
    lstm_persist<false><<<NBLK, 512, 0, stream>>>(x, xh, Wf, h0, h1, out, slots, done);
  }
}

// Round 18
// 5667.751 us; speedup vs baseline: 1.2692x; 1.2692x over previous
//
#include <hip/hip_runtime.h>
#include <cstdint>
#include <cstddef>

#define B_ 64
#define T_ 1024
#define D_ 1024
#define NBLK 256

typedef __attribute__((ext_vector_type(8))) _Float16 half8;
typedef __attribute__((ext_vector_type(4))) float f32x4;
typedef unsigned int u32;
typedef unsigned long long u64;
typedef unsigned short u16;

static __device__ __forceinline__ f32x4 mfma16(half8 a, half8 b, f32x4 c) {
  return __builtin_amdgcn_mfma_f32_16x16x32_f16(a, b, c, 0, 0, 0);
}
static __device__ __forceinline__ u64 cohl64(const u64* p) {
  return __hip_atomic_load(p, __ATOMIC_RELAXED, __HIP_MEMORY_SCOPE_AGENT);
}
static __device__ __forceinline__ u32 cohl32(const u32* p) {
  return __hip_atomic_load(p, __ATOMIC_RELAXED, __HIP_MEMORY_SCOPE_AGENT);
}
static __device__ __forceinline__ void cohs32(u32* p, u32 v) {
  __hip_atomic_store(p, v, __ATOMIC_RELAXED, __HIP_MEMORY_SCOPE_AGENT);
}
static __device__ __forceinline__ u16 h2u(_Float16 h) {
  return __builtin_bit_cast(u16, h);
}

// ---- staging: 32 rows x 1024 fp16 -> regs -> LDS (XOR-swizzled) ----------
// 512 threads: thread t covers rows r=t>>5 and r+16, chunk j=t&31.

static __device__ __forceinline__ void stage_coh(const _Float16* src, u64* st, int tid) {
  const int r = tid >> 5, j = tid & 31;
  const u64* p0 = (const u64*)(src + (size_t)r * D_) + j * 2;
  const u64* p1 = (const u64*)(src + (size_t)(r + 16) * D_) + j * 2;
  #pragma unroll
  for (int k = 0; k < 4; ++k) {
    st[2 * k] = cohl64(p0 + k * 64);
    st[2 * k + 1] = cohl64(p0 + k * 64 + 1);
    st[8 + 2 * k] = cohl64(p1 + k * 64);
    st[8 + 2 * k + 1] = cohl64(p1 + k * 64 + 1);
  }
}
static __device__ __forceinline__ void stage_x(const _Float16* src, u64* st, int tid) {
  const int r = tid >> 5, j = tid & 31;
  const u64* p0 = (const u64*)(src + (size_t)r * T_ * D_) + j * 2;
  const u64* p1 = (const u64*)(src + (size_t)(r + 16) * T_ * D_) + j * 2;
  #pragma unroll
  for (int k = 0; k < 4; ++k) {
    st[2 * k] = p0[k * 64];
    st[2 * k + 1] = p0[k * 64 + 1];
    st[8 + 2 * k] = p1[k * 64];
    st[8 + 2 * k + 1] = p1[k * 64 + 1];
  }
}
static __device__ __forceinline__ void stage_xf(const float* src, u64* st, int tid) {
  const int r = tid >> 5, j = tid & 31;
  #pragma unroll
  for (int h = 0; h < 2; ++h) {
    const float4* p = (const float4*)(src + (size_t)(r + h * 16) * T_ * D_) + j * 2;
    #pragma unroll
    for (int k = 0; k < 4; ++k) {
      #pragma unroll
      for (int q = 0; q < 2; ++q) {
        float4 v = p[k * 64 + q];
        union { u16 us[4]; u64 u; } pk;
        pk.us[0] = h2u((_Float16)v.x); pk.us[1] = h2u((_Float16)v.y);
        pk.us[2] = h2u((_Float16)v.z); pk.us[3] = h2u((_Float16)v.w);
        st[h * 8 + 2 * k + q] = pk.u;
      }
    }
  }
}
static __device__ __forceinline__ void stage_write(char* lds, const u64* st, int tid) {
  const int r = tid >> 5, j = tid & 31;
  #pragma unroll
  for (int h = 0; h < 2; ++h) {
    const int rr = r + h * 16;
    const int sw = (rr & 7) << 4;
    char* row = lds + rr * 2048;
    #pragma unroll
    for (int k = 0; k < 4; ++k) {
      char* dst = row + ((j * 16 + k * 512) ^ sw);
      *(u64*)dst = st[h * 8 + 2 * k];
      *(u64*)(dst + 8) = st[h * 8 + 2 * k + 1];
    }
  }
}

// ---- GEMM: gate-pair, weights pinned in regs. 1 A-pair -> 4 MFMAs --------
static __device__ __forceinline__ void gemm_gp(
    f32x4* acc, const char* ldsA, const half8* wA, const half8* wBv,
    int kq, int lane) {
  const int r = lane & 15;
  const int kl2 = (lane >> 4) << 4;
  const int sw = (r & 7) << 4;
  const char* p0 = ldsA + r * 2048;
  const char* p1 = ldsA + (16 + r) * 2048;   // (16+r)&7 == r&7: same swizzle
  #pragma unroll
  for (int ks = 0; ks < 8; ++ks) {
    const int kb = (kq * 512 + ks * 64 + kl2) ^ sw;
    half8 a0 = *(const half8*)(p0 + kb);
    half8 a1 = *(const half8*)(p1 + kb);
    acc[0] = mfma16(a0, wA[ks], acc[0]);
    acc[1] = mfma16(a1, wA[ks], acc[1]);
    acc[2] = mfma16(a0, wBv[ks], acc[2]);
    acc[3] = mfma16(a1, wBv[ks], acc[3]);
  }
}

// r13/r16 scatter wait (split-group), bounded — measured-best barrier
static __device__ __forceinline__ void pollwait2(const u32* slots, u32 gen0,
                                                 u32 gen1, int tid) {
  if (tid < NBLK) {
    const u32 tgt = (tid < 128) ? gen0 : gen1;
    if (tgt > 0) {
      const u32* p = slots + tid * 32;
      int spin = 0;
      while (cohl32(p) < tgt && ++spin < (1 << 16))
        __builtin_amdgcn_s_sleep(2);
    }
  }
  __syncthreads();
}

// ---- persistent kernel ---------------------------------------------------
// r16 champion structure + double-buffer ONLY (the good half of r17):
// bufA/bufB (128KB); glp aliases bufA (dead after GEMM1 at sync B);
// removes the anti-WAR sync between GEMM1 and re-staging.
// Barrier stays r16 scatter (tree's 3-hop detect cost +1.4us/step — r17).
// Order per step: wait -> stage op1->bufA -> syncA -> issue op2 loads ->
// GEMM1(bufA) [op2 latency hides] -> write bufB -> syncB -> GEMM2(bufB)
// -> glp(=bufA) -> syncC -> cell -> syncD -> arrive -> x prefetch.

template <bool XPRE>
__global__ __launch_bounds__(512, 2) void lstm_persist(
    const float* __restrict__ x32, const _Float16* __restrict__ xh,
    const _Float16* __restrict__ W,
    _Float16* h0,                  // [8 rot][B][D]
    _Float16* h1,                  // [2 parity][B][D]
    float* __restrict__ out, u32* slots)
{
  __shared__ char bufA[65536];
  __shared__ char bufB[65536];
  float (*glp)[32][68] = (float (*)[32][68])bufA;   // alias (bufA dead)

  const int tid = threadIdx.x;
  const int lane = tid & 63;
  const int wv = tid >> 6;                 // 0..7
  const int kq = wv >> 1;
  const int gp = wv & 1;
  const int bid = blockIdx.x;
  const int slot = bid >> 3;
  const int lyr = slot >> 4;
  const int mh = (slot >> 3) & 1;
  const int dgrp = (bid & 7) * 8 + (slot & 7);
  const int d0 = dgrp << 4;
  const int mbase = mh << 5;
  const int r = lane & 15;
  const int klane = lane >> 4;

  // ---- weight preload: 2 gates x (Wih+Whh) = 32 half8, pinned ----
  const _Float16* Wih = W + (size_t)(2 * lyr) * 4096 * 1024;
  const _Float16* Whh = Wih + (size_t)4096 * 1024;
  const size_t row0 = (size_t)((gp * 2) * 1024 + d0 + r) * 1024 + kq * 256 + klane * 8;
  const size_t row1 = (size_t)((gp * 2 + 1) * 1024 + d0 + r) * 1024 + kq * 256 + klane * 8;
  half8 wihA[8], wihB[8], whhA[8], whhB[8];
  #pragma unroll
  for (int ks = 0; ks < 8; ++ks) {
    wihA[ks] = *(const half8*)(Wih + row0 + ks * 32);
    wihB[ks] = *(const half8*)(Wih + row1 + ks * 32);
    whhA[ks] = *(const half8*)(Whh + row0 + ks * 32);
    whhB[ks] = *(const half8*)(Whh + row1 + ks * 32);
  }
  #pragma unroll
  for (int ks = 0; ks < 8; ++ks) {
    asm volatile("" : "+v"(wihA[ks]));
    asm volatile("" : "+v"(wihB[ks]));
    asm volatile("" : "+v"(whhA[ks]));
    asm volatile("" : "+v"(whhB[ks]));
  }

  float creg0 = 0.f, creg1 = 0.f;
  const int cb = tid >> 3;
  const int cd = (tid & 7) << 1;
  const size_t HS = (size_t)B_ * D_;

  u64 st[16];
  if (lyr == 0) {
    if (XPRE) stage_x(xh + (size_t)mbase * T_ * D_, st, tid);
    else      stage_xf(x32 + (size_t)mbase * T_ * D_, st, tid);
  }

  for (int s = 0; s <= T_; ++s) {
    const bool active = lyr ? (s >= 1) : (s < T_);
    const int t = lyr ? (s - 1) : s;

    if (lyr == 0)
      pollwait2(slots, (u32)s, (u32)(s > 4 ? s - 4 : 0), tid);
    else
      pollwait2(slots, (u32)s, (u32)s, tid);

    if (active) {
      const _Float16* h0prev = h0 + (size_t)((s + 7) & 7) * HS + (size_t)mbase * D_;
      // stage operand 1 into bufA
      if (lyr == 0) {
        stage_write(bufA, st, tid);            // x[t] (prefetched regs)
      } else {
        stage_coh(h0prev, st, tid);            // h0[t] from layer 0
        stage_write(bufA, st, tid);            // (waits its loads)
      }
      __syncthreads();                         // A: bufA ready

      // issue operand-2 loads; their latency hides under GEMM1
      if (lyr == 0) stage_coh(h0prev, st, tid);
      else          stage_coh(h1 + (size_t)(s & 1) * HS + (size_t)mbase * D_, st, tid);

      f32x4 acc[4];
      #pragma unroll
      for (int i = 0; i < 4; ++i) acc[i] = (f32x4){0.f, 0.f, 0.f, 0.f};
      gemm_gp(acc, bufA, wihA, wihB, kq, lane);    // GEMM1
      stage_write(bufB, st, tid);                  // op2 -> bufB (no WAR sync!)
      __syncthreads();                             // B: bufB ready, bufA dead
      gemm_gp(acc, bufB, whhA, whhB, kq, lane);    // GEMM2 (accumulates)

      // partials -> glp (aliases bufA; all bufA reads done at sync B)
      {
        const int r4 = klane << 2;
        const int c0 = (gp * 2) * 16 + r;
        #pragma unroll
        for (int i = 0; i < 4; ++i) {
          glp[kq][r4 + i][c0]           = acc[0][i];
          glp[kq][16 + r4 + i][c0]      = acc[1][i];
          glp[kq][r4 + i][c0 + 16]      = acc[2][i];
          glp[kq][16 + r4 + i][c0 + 16] = acc[3][i];
        }
      }
      __syncthreads();                             // C: glp ready

      if (tid < 256) {
        float g4[4][2];
        #pragma unroll
        for (int gg = 0; gg < 4; ++gg) {
          g4[gg][0] = glp[0][cb][gg * 16 + cd] + glp[1][cb][gg * 16 + cd]
                    + glp[2][cb][gg * 16 + cd] + glp[3][cb][gg * 16 + cd];
          g4[gg][1] = glp[0][cb][gg * 16 + cd + 1] + glp[1][cb][gg * 16 + cd + 1]
                    + glp[2][cb][gg * 16 + cd + 1] + glp[3][cb][gg * 16 + cd + 1];
        }
        const float i0 = 1.f / (1.f + expf(-g4[0][0])), i1 = 1.f / (1.f + expf(-g4[0][1]));
        const float f0 = 1.f / (1.f + expf(-g4[1][0])), f1 = 1.f / (1.f + expf(-g4[1][1]));
        const float z0 = tanhf(g4[2][0]),               z1 = tanhf(g4[2][1]);
        const float o0 = 1.f / (1.f + expf(-g4[3][0])), o1 = 1.f / (1.f + expf(-g4[3][1]));
        creg0 = f0 * creg0 + i0 * z0;
        creg1 = f1 * creg1 + i1 * z1;
        const float hn0 = o0 * tanhf(creg0);
        const float hn1 = o1 * tanhf(creg1);
        union { u16 us[2]; u32 u; } pk;
        pk.us[0] = h2u((_Float16)hn0);
        pk.us[1] = h2u((_Float16)hn1);
        _Float16* hw = lyr
            ? (h1 + (size_t)((s + 1) & 1) * HS)
            : (h0 + (size_t)(s & 7) * HS);
        cohs32((u32*)(hw + (size_t)(mbase + cb) * D_ + d0 + cd), pk.u);
        if (lyr) {
          float2 o2; o2.x = hn0; o2.y = hn1;
          *(float2*)(out + ((size_t)(mbase + cb) * T_ + t) * D_ + d0 + cd) = o2;
        }
      }
    }

    // drain sc1 h stores (syncthreads emits vmcnt(0) per wave), then arrive
    __syncthreads();                               // D
    if (tid == 0) cohs32(slots + bid * 32, (u32)(s + 1));

    // prefetch next x after arrive
    if (lyr == 0 && s + 1 < T_) {
      if (XPRE) stage_x(xh + ((size_t)mbase * T_ + (s + 1)) * D_, st, tid);
      else      stage_xf(x32 + ((size_t)mbase * T_ + (s + 1)) * D_, st, tid);
    }
  }
}

// ---- setup ---------------------------------------------------------------
__global__ void convw(const float* __restrict__ w0, const float* __restrict__ w1,
                      const float* __restrict__ w2, const float* __restrict__ w3,
                      u64* __restrict__ dst) {
  const size_t n1 = (size_t)D_ * D_;
  const size_t n = 4 * n1;
  for (size_t i = (size_t)blockIdx.x * blockDim.x + threadIdx.x; i < n;
       i += (size_t)gridDim.x * blockDim.x) {
    const size_t m = i / n1, j = i - m * n1;
    const float* src = (m == 0) ? w0 : (m == 1) ? w1 : (m == 2) ? w2 : w3;
    float4 v = ((const float4*)src)[j];
    union { u16 us[4]; u64 u; } pk;
    pk.us[0] = h2u((_Float16)v.x); pk.us[1] = h2u((_Float16)v.y);
    pk.us[2] = h2u((_Float16)v.z); pk.us[3] = h2u((_Float16)v.w);
    dst[i] = pk.u;
  }
}
__global__ void convx(const float* __restrict__ x, u64* __restrict__ xh) {
  const size_t n = (size_t)B_ * T_ * D_ / 4;
  for (size_t i = (size_t)blockIdx.x * blockDim.x + threadIdx.x; i < n;
       i += (size_t)gridDim.x * blockDim.x) {
    float4 v = ((const float4*)x)[i];
    union { u16 us[4]; u64 u; } pk;
    pk.us[0] = h2u((_Float16)v.x); pk.us[1] = h2u((_Float16)v.y);
    pk.us[2] = h2u((_Float16)v.z); pk.us[3] = h2u((_Float16)v.w);
    xh[i] = pk.u;
  }
}

// ---- host ----------------------------------------------------------------
extern "C" void kernel_launch(void* const* d_in, const int* in_sizes, int n_in,
                              void* d_out, int out_size, void* d_ws, size_t ws_size,
                              hipStream_t stream) {
  (void)in_sizes; (void)n_in; (void)out_size;
  const float* x = (const float*)d_in[0];
  const float* Wih0 = (const float*)d_in[1];
  const float* Whh0 = (const float*)d_in[2];
  const float* Wih1 = (const float*)d_in[3];
  const float* Whh1 = (const float*)d_in[4];
  float* out = (float*)d_out;

  char* ws = (char*)d_ws;
  const size_t MB = 1ull << 20;
  const size_t KB = 1024;
  // layout: [0,32MB) W fp16
  //   32MB: h0 rot8 1MB | 33MB: h1 256KB | +256KB: slots 32KB | 35MB: xh
  _Float16* Wf = (_Float16*)ws;
  _Float16* h0 = (_Float16*)(ws + 32 * MB);
  _Float16* h1 = (_Float16*)(ws + 33 * MB);
  u32* slots = (u32*)(ws + 33 * MB + 256 * KB);
  _Float16* xh = (_Float16*)(ws + 35 * MB);
  const bool xpre = ws_size >= 35 * MB + (size_t)B_ * T_ * D_ * 2;

  hipMemsetAsync(ws + 32 * MB, 0, 1 * MB + 256 * KB + 32 * KB, stream);
  convw<<<4096, 256, 0, stream>>>(Wih0, Whh0, Wih1, Whh1, (u64*)Wf);
  if (xpre) {
    convx<<<4096, 256, 0, stream>>>(x, (u64*)xh);
    lstm_persist<true><<<NBLK, 512, 0, stream>>>(x, xh, Wf, h0, h1, out, slots);
  } else {
    lstm_persist<false><<<NBLK, 512, 0, stream>>>(x, xh, Wf, h0, h1, out, slots);
  }
}